// Round 1
// baseline (111.413 us; speedup 1.0000x reference)
//
#include <hip/hip_runtime.h>

typedef unsigned short u16;
typedef unsigned int u32;
typedef unsigned long long u64;

#define VOCAB 50000
#define BATCH 2048
#define NTOP 64
#define RHO 0.1f

#define KSPLIT 16
#define CHUNK 3136   // 49*64; last chunk covers 47040..50000 (tail masked)
#define BM 64
#define BK 64

typedef short bf16x8 __attribute__((ext_vector_type(8)));
typedef short bf16x4 __attribute__((ext_vector_type(4)));
typedef float f32x4 __attribute__((ext_vector_type(4)));

__device__ __forceinline__ u16 f32_to_bf16(float f) {
  u32 u = __builtin_bit_cast(u32, f);
  return (u16)((u + 0x8000u) >> 16);   // round-half-up; plenty for this tolerance
}
__device__ __forceinline__ u32 pack2(float a, float b) {
  return (u32)f32_to_bf16(a) | ((u32)f32_to_bf16(b) << 16);
}

// Kernel 1: beta f32 -> bf16 into ws, and zero the s accumulator.
__global__ void ctm_prep(const float* __restrict__ beta, u16* __restrict__ beta16,
                         float* __restrict__ s) {
  int i = blockIdx.x * blockDim.x + threadIdx.x;
  int stride = gridDim.x * blockDim.x;
  for (int j = i; j < (BATCH * NTOP / 4); j += stride)
    ((float4*)s)[j] = make_float4(0.f, 0.f, 0.f, 0.f);
  for (int j = i; j < (NTOP * VOCAB / 4); j += stride) {
    float4 v = ((const float4*)beta)[j];
    u32 lo = pack2(v.x, v.y);
    u32 hi = pack2(v.z, v.w);
    ((uint2*)beta16)[j] = make_uint2(lo, hi);
  }
}

// Kernel 2: s += x[row0:row0+64, k0:kend] @ beta16[:, k0:kend]^T  via bf16 MFMA.
// LDS tiles stored [row][k] bf16 with byte-XOR swizzle: byte = row*128 + ((2k) ^ ((row&7)<<4))
__global__ void __launch_bounds__(256) ctm_gemm(const float* __restrict__ x,
                                                const u16* __restrict__ beta16,
                                                float* __restrict__ s) {
  __shared__ u16 ldsA[BM * BK];
  __shared__ u16 ldsB[NTOP * BK];

  const int t = threadIdx.x;
  const int l = t & 63;
  const int w = t >> 6;
  const int k0 = blockIdx.x * CHUNK;
  const int row0 = blockIdx.y * BM;
  const int kend = (k0 + CHUNK < VOCAB) ? (k0 + CHUNK) : VOCAB;
  const int nsteps = (kend - k0 + BK - 1) >> 6;

  // A staging: thread t handles row=t/4, 16 consecutive k at offset (t%4)*16
  const int arow = t >> 2;
  const int akq = (t & 3) << 4;
  const u64 xbase = (u64)(row0 + arow) * VOCAB;
  const u32 aswz = (u32)((arow & 7) << 4);
  const u32 abyte0 = (u32)(arow * 128) + (((u32)(akq * 2)) ^ aswz);
  const u32 abyte1 = (u32)(arow * 128) + (((u32)(akq * 2 + 16)) ^ aswz);

  // B staging via global_load_lds: LDS linear dest (base + lane*16), source
  // pre-swizzled so that content lands at swizzled position.
  const int bp0 = t * 16;
  const int bp1 = 4096 + t * 16;
  const int bcol0 = bp0 >> 7, bcol1 = bp1 >> 7;
  const int bk0 = ((bp0 & 127) ^ ((bcol0 & 7) << 4)) >> 1;
  const int bk1 = ((bp1 & 127) ^ ((bcol1 & 7) << 4)) >> 1;
  const u64 bsrc0 = (u64)bcol0 * VOCAB + (u64)bk0;
  const u64 bsrc1 = (u64)bcol1 * VOCAB + (u64)bk1;
  const u32 ldsb_base0 = (u32)(w * 1024) >> 1;          // ushort index, wave-uniform
  const u32 ldsb_base1 = (u32)(4096 + w * 1024) >> 1;

  // MFMA fragment indices (16x16x32: lane holds row/col = l&15; k-subgroup l>>4)
  const int fr = l & 15;
  const int fk = l >> 4;
  const int arow_f = (w << 4) | fr;
  const u32 aswz_f = (u32)((arow_f & 7) << 4);

  f32x4 acc[4] = {{0.f,0.f,0.f,0.f},{0.f,0.f,0.f,0.f},{0.f,0.f,0.f,0.f},{0.f,0.f,0.f,0.f}};

  for (int st = 0; st < nsteps; ++st) {
    const int ks0 = k0 + (st << 6);

    // B tile: 2 async direct-to-LDS loads per wave (16B/lane)
    __builtin_amdgcn_global_load_lds(
        (const __attribute__((address_space(1))) void*)(beta16 + bsrc0 + (u64)ks0),
        (__attribute__((address_space(3))) void*)(&ldsB[ldsb_base0]), 16, 0, 0);
    __builtin_amdgcn_global_load_lds(
        (const __attribute__((address_space(1))) void*)(beta16 + bsrc1 + (u64)ks0),
        (__attribute__((address_space(3))) void*)(&ldsB[ldsb_base1]), 16, 0, 0);

    // A tile: f32 load -> bf16 convert -> swizzled ds_write_b128 x2
    float4 v0, v1, v2, v3;
    if (ks0 + BK <= kend) {
      const float4* xp = (const float4*)(x + xbase + ks0 + akq);
      v0 = xp[0]; v1 = xp[1]; v2 = xp[2]; v3 = xp[3];
    } else {
      float tmp[16];
      #pragma unroll
      for (int e = 0; e < 16; ++e) {
        int k = ks0 + akq + e;
        tmp[e] = (k < kend) ? x[xbase + k] : 0.0f;
      }
      v0 = make_float4(tmp[0], tmp[1], tmp[2], tmp[3]);
      v1 = make_float4(tmp[4], tmp[5], tmp[6], tmp[7]);
      v2 = make_float4(tmp[8], tmp[9], tmp[10], tmp[11]);
      v3 = make_float4(tmp[12], tmp[13], tmp[14], tmp[15]);
    }
    uint4 pk0, pk1;
    pk0.x = pack2(v0.x, v0.y); pk0.y = pack2(v0.z, v0.w);
    pk0.z = pack2(v1.x, v1.y); pk0.w = pack2(v1.z, v1.w);
    pk1.x = pack2(v2.x, v2.y); pk1.y = pack2(v2.z, v2.w);
    pk1.z = pack2(v3.x, v3.y); pk1.w = pack2(v3.z, v3.w);
    *(uint4*)(&ldsA[abyte0 >> 1]) = pk0;
    *(uint4*)(&ldsA[abyte1 >> 1]) = pk1;

    __syncthreads();

    #pragma unroll
    for (int ks = 0; ks < 2; ++ks) {
      const u32 in0 = (u32)(ks * 64 + fk * 8);   // byte offset of regs 0-3 (k-half 0)
      const u32 in1 = in0 + 32;                  // regs 4-7 (k-half 1)
      union { bf16x4 h[2]; bf16x8 v; } ua;
      ua.h[0] = *(const bf16x4*)(&ldsA[((u32)(arow_f * 128) + (in0 ^ aswz_f)) >> 1]);
      ua.h[1] = *(const bf16x4*)(&ldsA[((u32)(arow_f * 128) + (in1 ^ aswz_f)) >> 1]);
      #pragma unroll
      for (int n = 0; n < 4; ++n) {
        const int bcol = (n << 4) | fr;
        const u32 bswz = (u32)((bcol & 7) << 4);
        union { bf16x4 h[2]; bf16x8 v; } ub;
        ub.h[0] = *(const bf16x4*)(&ldsB[((u32)(bcol * 128) + (in0 ^ bswz)) >> 1]);
        ub.h[1] = *(const bf16x4*)(&ldsB[((u32)(bcol * 128) + (in1 ^ bswz)) >> 1]);
        acc[n] = __builtin_amdgcn_mfma_f32_16x16x32_bf16(ua.v, ub.v, acc[n], 0, 0, 0);
      }
    }
    __syncthreads();
  }

  // C/D layout: col = l&15, row = (l>>4)*4 + reg
  #pragma unroll
  for (int n = 0; n < 4; ++n) {
    #pragma unroll
    for (int r = 0; r < 4; ++r) {
      const int row = row0 + (w << 4) + (fk << 2) + r;
      const int col = (n << 4) | fr;
      atomicAdd(&s[row * NTOP + col], acc[n][r]);
    }
  }
}

// Kernel 3: out[b,k] = s[b,k] + mu[k] + RHO*(sum_j theta[k,j]*s[b,j] - theta[k,k]*s[b,k])
__global__ void __launch_bounds__(256) ctm_epi(const float* __restrict__ s,
                                               const float* __restrict__ theta,
                                               const float* __restrict__ mu,
                                               float* __restrict__ out) {
  __shared__ float thT[NTOP * NTOP];  // thT[j*64+k] = theta[k][j]
  __shared__ float sb[8 * NTOP];
  const int t = threadIdx.x;
  const int r0 = blockIdx.x * 8;

  #pragma unroll
  for (int i = 0; i < 16; ++i) {
    int e = i * 256 + t;                 // coalesced read of theta
    thT[(e & 63) * 64 + (e >> 6)] = theta[e];
  }
  sb[t] = s[r0 * 64 + t];
  sb[t + 256] = s[r0 * 64 + 256 + t];
  __syncthreads();

  const int k = t & 63;
  const int rl = t >> 6;
  const float muk = mu[k];
  const float diag = thT[k * 64 + k];
  #pragma unroll
  for (int rr = 0; rr < 2; ++rr) {
    const int r = rl + rr * 4;
    const float* srow = &sb[r * 64];
    float accv = 0.f;
    #pragma unroll 8
    for (int j = 0; j < 64; ++j)
      accv += thT[j * 64 + k] * srow[j];   // thT: consecutive lanes consecutive; srow: broadcast
    const float sv = srow[k];
    out[(r0 + r) * 64 + k] = sv + muk + RHO * (accv - diag * sv);
  }
}

extern "C" void kernel_launch(void* const* d_in, const int* in_sizes, int n_in,
                              void* d_out, int out_size, void* d_ws, size_t ws_size,
                              hipStream_t stream) {
  const float* x = (const float*)d_in[0];
  const float* beta = (const float*)d_in[1];
  const float* theta = (const float*)d_in[2];
  const float* mu = (const float*)d_in[3];
  float* out = (float*)d_out;

  // ws layout: [0, 6.4MB) beta bf16; [6.4MB, +512KB) s accumulator. Needs ~6.9MB.
  u16* beta16 = (u16*)d_ws;
  float* s = (float*)((char*)d_ws + (size_t)NTOP * VOCAB * 2);

  ctm_prep<<<2048, 256, 0, stream>>>(beta, beta16, s);
  ctm_gemm<<<dim3(KSPLIT, BATCH / BM), 256, 0, stream>>>(x, beta16, s);
  ctm_epi<<<BATCH / 8, 256, 0, stream>>>(s, theta, mu, out);
}